// Round 6
// baseline (236.407 us; speedup 1.0000x reference)
//
#include <hip/hip_runtime.h>

#define NN 50000
#define NE 800000
#define DD 128
#define ED 32
#define NB 196    // ceil(NN/256)
#define NCH (NE / 16)   // 50000 exact

typedef short bf16x8 __attribute__((ext_vector_type(8)));
typedef float f32x4  __attribute__((ext_vector_type(4)));

__device__ __forceinline__ float4 ld4(const float* p) {
    return *reinterpret_cast<const float4*>(p);
}
__device__ __forceinline__ short f2bf(float f) {   // RTN-even f32 -> bf16 bits
    unsigned u = __float_as_uint(f);
    u += 0x7fffu + ((u >> 16) & 1u);
    return (short)(u >> 16);
}
__device__ __forceinline__ float bf2f(short h) {
    return __uint_as_float(((unsigned)(unsigned short)h) << 16);
}
__device__ __forceinline__ int sniff64(const int* ei) {
    // int64 indices < 2^32: every odd 32-bit word is zero.
    return ((ei[1] | ei[3] | ei[5] | ei[7]) == 0) ? 1 : 0;
}

// ============================================================ CSR build
__global__ __launch_bounds__(256)
void k_hist(const int* __restrict__ ei, int* __restrict__ counts) {
    const int is64 = sniff64(ei);
    for (int e = blockIdx.x * blockDim.x + threadIdx.x; e < NE;
         e += gridDim.x * blockDim.x) {
        const int dst = ei[(long)(NE + e) << is64];
        atomicAdd(&counts[dst], 1);
    }
}

__global__ __launch_bounds__(256)
void k_bsum(const int* __restrict__ counts, int* __restrict__ bsum) {
    const int i = blockIdx.x * 256 + threadIdx.x;
    int c = (i < NN) ? counts[i] : 0;
#pragma unroll
    for (int off = 32; off; off >>= 1) c += __shfl_xor(c, off, 64);
    __shared__ int ws4[4];
    if ((threadIdx.x & 63) == 0) ws4[threadIdx.x >> 6] = c;
    __syncthreads();
    if (threadIdx.x == 0) bsum[blockIdx.x] = ws4[0] + ws4[1] + ws4[2] + ws4[3];
}

__global__ __launch_bounds__(256)
void k_scanb(const int* __restrict__ bsum, int* __restrict__ bexcl) {
    const int tid = threadIdx.x, lane = tid & 63, w = tid >> 6;
    const int v = (tid < NB) ? bsum[tid] : 0;
    int s = v;
#pragma unroll
    for (int off = 1; off < 64; off <<= 1) {
        const int t = __shfl_up(s, off, 64);
        if (lane >= off) s += t;
    }
    __shared__ int wsum[4], wexcl[4];
    if (lane == 63) wsum[w] = s;
    __syncthreads();
    if (tid == 0) {
        int r = 0;
#pragma unroll
        for (int k = 0; k < 4; ++k) { wexcl[k] = r; r += wsum[k]; }
    }
    __syncthreads();
    if (tid < NB) bexcl[tid] = wexcl[w] + s - v;
}

__global__ __launch_bounds__(256)
void k_rowptr(const int* __restrict__ counts, const int* __restrict__ bexcl,
              int* __restrict__ cursor) {
    const int tid = threadIdx.x, lane = tid & 63, w = tid >> 6;
    const int i = blockIdx.x * 256 + tid;
    const int c = (i < NN) ? counts[i] : 0;
    int s = c;
#pragma unroll
    for (int off = 1; off < 64; off <<= 1) {
        const int t = __shfl_up(s, off, 64);
        if (lane >= off) s += t;
    }
    __shared__ int wsum[4], wexcl[4];
    if (lane == 63) wsum[w] = s;
    __syncthreads();
    if (tid == 0) {
        int r = 0;
#pragma unroll
        for (int k = 0; k < 4; ++k) { wexcl[k] = r; r += wsum[k]; }
    }
    __syncthreads();
    if (i < NN) cursor[i] = bexcl[blockIdx.x] + wexcl[w] + s - c;
}

__global__ __launch_bounds__(256)
void k_scatter(const int* __restrict__ ei, int* __restrict__ cursor,
               int2* __restrict__ sdat, int* __restrict__ edst) {
    const int is64 = sniff64(ei);
    for (int e = blockIdx.x * blockDim.x + threadIdx.x; e < NE;
         e += gridDim.x * blockDim.x) {
        const int src = ei[(long)e << is64];
        const int dst = ei[(long)(NE + e) << is64];
        const int pos = atomicAdd(&cursor[dst], 1);
        sdat[pos] = make_int2(src, e);
        edst[pos] = dst;
    }
}

// ============================================================ aggregation
// Edge-parallel over 50000 uniform 16-edge chunks (dst-sorted), grid-stride
// with next-chunk descriptor prefetch. Per chunk: coalesced sdat/edst line,
// C-init = x[src] gathers, 8x mfma adds ea@We, relu(+be), then ballot/popc
// segmented reduction over equal-dst runs; one unsafeAtomicAdd pair per lane
// per segment (~2 segs/chunk avg). agg must be pre-zeroed.
__global__ __launch_bounds__(256, 4)
void k_aggE(const float* __restrict__ x, const float* __restrict__ ea,
            const float* __restrict__ We, const float* __restrict__ be,
            const int2* __restrict__ sdat, const int* __restrict__ edst,
            float* __restrict__ agg)
{
    const int lane = threadIdx.x & 63;
    const int ncol = lane & 15;
    const int krow = (lane >> 4) << 3;   // 0,8,16,24
    const int grp  = lane >> 4;
    const int wid  = (blockIdx.x << 2) | (threadIdx.x >> 6);
    const int nw   = gridDim.x << 2;

    // B fragments: Bf[b][i] = We[krow+i][16b+ncol]
    bf16x8 Bf[8];
    float beb[8];
#pragma unroll
    for (int b = 0; b < 8; ++b) {
#pragma unroll
        for (int i = 0; i < 8; ++i)
            Bf[b][i] = f2bf(We[(krow + i) * DD + b * 16 + ncol]);
        beb[b] = be[b * 16 + ncol];
    }

    if (wid >= NCH) return;

    // prologue: descriptors for first chunk (lane's edge = ncol)
    int2 dv   = sdat[wid * 16 + ncol];
    int  dstv = edst[wid * 16 + ncol];

    for (int c = wid; c < NCH; c += nw) {
        // prefetch next chunk's descriptors
        const int cn = min(c + nw, NCH - 1);
        const int2 dvn   = sdat[cn * 16 + ncol];
        const int  dstvn = edst[cn * 16 + ncol];

        // ea gather: lane reads its edge's row slice [krow, krow+8)
        const float* ear = ea + (size_t)dv.y * ED + krow;
        const float4 r0 = ld4(ear), r1 = ld4(ear + 4);

        // x gathers -> C-init: C[b][r] = x[src_{grp*4+r}][b*16+ncol]
        const float* xr[4];
#pragma unroll
        for (int r = 0; r < 4; ++r)
            xr[r] = x + (size_t)__shfl(dv.x, (grp << 2) + r, 64) * DD + ncol;
        f32x4 C[8];
#pragma unroll
        for (int b = 0; b < 8; ++b) {
            f32x4 cc;
            cc[0] = xr[0][b * 16]; cc[1] = xr[1][b * 16];
            cc[2] = xr[2][b * 16]; cc[3] = xr[3][b * 16];
            C[b] = cc;
        }

        bf16x8 Af;
        Af[0] = f2bf(r0.x); Af[1] = f2bf(r0.y);
        Af[2] = f2bf(r0.z); Af[3] = f2bf(r0.w);
        Af[4] = f2bf(r1.x); Af[5] = f2bf(r1.y);
        Af[6] = f2bf(r1.z); Af[7] = f2bf(r1.w);

#pragma unroll
        for (int b = 0; b < 8; ++b)
            C[b] = __builtin_amdgcn_mfma_f32_16x16x32_bf16(Af, Bf[b], C[b], 0, 0, 0);

        // relu'd messages: t[b][r] = msg[edge grp*4+r][dim b*16+ncol]
        float t[8][4];
#pragma unroll
        for (int b = 0; b < 8; ++b)
#pragma unroll
            for (int r = 0; r < 4; ++r)
                t[b][r] = fmaxf(C[b][r] + beb[b], 0.0f);

        // segment boundaries over the 16 dst-sorted edges
        const int prv = __shfl(dstv, (lane == 0) ? 0 : lane - 1, 64);
        const bool flag = (lane < 16) && ((ncol == 0) || (dstv != prv));
        const unsigned B16 = (unsigned)__ballot(flag) & 0xFFFFu;

        int sid[4];
#pragma unroll
        for (int r = 0; r < 4; ++r) {
            const int m = (grp << 2) + r;
            sid[r] = __popc(B16 & ((2u << m) - 1)) - 1;
        }

        unsigned rem = B16;
        int s = 0;
        while (rem) {
            const int ms = __ffs((int)rem) - 1;
            rem &= rem - 1;
            const int d = __shfl(dstv, ms, 64);
            float red[8];
#pragma unroll
            for (int b = 0; b < 8; ++b) {
                float v = ((sid[0] == s) ? t[b][0] : 0.0f)
                        + ((sid[1] == s) ? t[b][1] : 0.0f)
                        + ((sid[2] == s) ? t[b][2] : 0.0f)
                        + ((sid[3] == s) ? t[b][3] : 0.0f);
                v += __shfl_xor(v, 16, 64);
                v += __shfl_xor(v, 32, 64);
                red[b] = v;
            }
            float v0 = red[0], v1 = red[4];
            v0 = (grp == 1) ? red[1] : v0;
            v0 = (grp == 2) ? red[2] : v0;
            v0 = (grp == 3) ? red[3] : v0;
            v1 = (grp == 1) ? red[5] : v1;
            v1 = (grp == 2) ? red[6] : v1;
            v1 = (grp == 3) ? red[7] : v1;
            float* ar = agg + (size_t)d * DD;
            unsafeAtomicAdd(ar + lane, v0);
            unsafeAtomicAdd(ar + 64 + lane, v1);
            ++s;
        }

        dv = dvn; dstv = dstvn;
    }
}

// ============================================================ conv (MFMA)
// conv = (x + agg) @ Wc + bc via split-bf16 (hi+lo, 3 MFMAs). agg aliases
// the conv output buffer (d_out): each block reads only its own 16 rows
// of agg/x before writing conv over them -> in-place safe.
__global__ __launch_bounds__(256)
void k_conv(const float* __restrict__ x, const float* agg,
            const float* __restrict__ Wc, const float* __restrict__ bc,
            float* conv)
{
    __shared__ short sBh[2048 * 8];
    __shared__ short sBl[2048 * 8];
    for (int idx = threadIdx.x; idx < 2048; idx += 256) {
        const int kk = idx >> 9;
        const int b  = (idx >> 6) & 7;
        const int l  = idx & 63;
        const int row0 = kk * 32 + ((l >> 4) << 3);
        const int col  = b * 16 + (l & 15);
        bf16x8 h8, l8;
#pragma unroll
        for (int j = 0; j < 8; ++j) {
            const float v = Wc[(row0 + j) * DD + col];
            const short h = f2bf(v);
            h8[j] = h;
            l8[j] = f2bf(v - bf2f(h));
        }
        *reinterpret_cast<bf16x8*>(&sBh[idx * 8]) = h8;
        *reinterpret_cast<bf16x8*>(&sBl[idx * 8]) = l8;
    }
    __syncthreads();

    const int lane = threadIdx.x & 63;
    const int ncol = lane & 15;
    const int krow = (lane >> 4) << 3;
    const int grp  = lane >> 4;
    const int wid  = (blockIdx.x << 2) | (threadIdx.x >> 6);
    if (wid >= NN / 16) return;

    float bcb[8];
#pragma unroll
    for (int b = 0; b < 8; ++b) bcb[b] = bc[b * 16 + ncol];

    const int m0 = wid * 16;
    const float* xrow = x   + (size_t)(m0 + ncol) * DD + krow;
    const float* grow = agg + (size_t)(m0 + ncol) * DD + krow;

    f32x4 C[8];
#pragma unroll
    for (int b = 0; b < 8; ++b) {
        f32x4 c = { bcb[b], bcb[b], bcb[b], bcb[b] };
        C[b] = c;
    }

#pragma unroll
    for (int kk = 0; kk < 4; ++kk) {
        const float4 x0 = ld4(xrow + kk * 32), x1 = ld4(xrow + kk * 32 + 4);
        const float4 g0 = ld4(grow + kk * 32), g1 = ld4(grow + kk * 32 + 4);
        const float av[8] = { x0.x + g0.x, x0.y + g0.y, x0.z + g0.z, x0.w + g0.w,
                              x1.x + g1.x, x1.y + g1.y, x1.z + g1.z, x1.w + g1.w };
        bf16x8 Ah, Al;
#pragma unroll
        for (int j = 0; j < 8; ++j) {
            const short h = f2bf(av[j]);
            Ah[j] = h;
            Al[j] = f2bf(av[j] - bf2f(h));
        }
#pragma unroll
        for (int b = 0; b < 8; ++b) {
            const bf16x8 Bh = *reinterpret_cast<const bf16x8*>(&sBh[((kk * 8 + b) * 64 + lane) * 8]);
            const bf16x8 Bl = *reinterpret_cast<const bf16x8*>(&sBl[((kk * 8 + b) * 64 + lane) * 8]);
            C[b] = __builtin_amdgcn_mfma_f32_16x16x32_bf16(Ah, Bh, C[b], 0, 0, 0);
            C[b] = __builtin_amdgcn_mfma_f32_16x16x32_bf16(Al, Bh, C[b], 0, 0, 0);
            C[b] = __builtin_amdgcn_mfma_f32_16x16x32_bf16(Ah, Bl, C[b], 0, 0, 0);
        }
    }

#pragma unroll
    for (int r = 0; r < 4; ++r) {
        float* crow = conv + (size_t)(m0 + (grp << 2) + r) * DD + ncol;
#pragma unroll
        for (int b = 0; b < 8; ++b) crow[b * 16] = C[b][r];
    }
}

// ============================================================ gate (MFMA)
__global__ __launch_bounds__(256)
void k_gate(const float* __restrict__ x, const float* conv,
            const float* __restrict__ imp, const float* __restrict__ Wg,
            const float* __restrict__ bg, const float* __restrict__ Wp,
            const float* __restrict__ bp, float* outp, float* __restrict__ prop)
{
    __shared__ short sBh[2048 * 8];
    __shared__ short sBl[2048 * 8];
    for (int idx = threadIdx.x; idx < 2048; idx += 256) {
        const int kk = idx >> 9;
        const int b  = (idx >> 6) & 7;
        const int l  = idx & 63;
        const int row0 = kk * 32 + ((l >> 4) << 3);
        const int col  = b * 16 + (l & 15);
        bf16x8 h8, l8;
#pragma unroll
        for (int j = 0; j < 8; ++j) {
            const float v = Wg[(row0 + j) * DD + col];
            const short h = f2bf(v);
            h8[j] = h;
            l8[j] = f2bf(v - bf2f(h));
        }
        *reinterpret_cast<bf16x8*>(&sBh[idx * 8]) = h8;
        *reinterpret_cast<bf16x8*>(&sBl[idx * 8]) = l8;
    }
    __syncthreads();

    const int lane = threadIdx.x & 63;
    const int ncol = lane & 15;
    const int krow = (lane >> 4) << 3;
    const int grp  = lane >> 4;
    const int wid  = (blockIdx.x << 2) | (threadIdx.x >> 6);
    if (wid >= NN / 16) return;

    float bgb[8], wgi[8], wp8[8];
#pragma unroll
    for (int b = 0; b < 8; ++b) {
        bgb[b] = bg[b * 16 + ncol];
        wgi[b] = Wg[DD * DD + b * 16 + ncol];   // importance row (row 128)
        wp8[b] = Wp[b * 16 + ncol];
    }
    const float bps = bp[0];

    const int m0 = wid * 16;

    float cvD[8][4], xvD[8][4], im[4];
#pragma unroll
    for (int r = 0; r < 4; ++r) {
        const int m = m0 + (grp << 2) + r;
        const float* cr = conv + (size_t)m * DD + ncol;
        const float* xr = x    + (size_t)m * DD + ncol;
        im[r] = imp[m];
#pragma unroll
        for (int b = 0; b < 8; ++b) { cvD[b][r] = cr[b * 16]; xvD[b][r] = xr[b * 16]; }
    }

    f32x4 C[8];
#pragma unroll
    for (int b = 0; b < 8; ++b) {
        f32x4 c = { bgb[b], bgb[b], bgb[b], bgb[b] };
        C[b] = c;
    }

    const float* arow = conv + (size_t)(m0 + ncol) * DD + krow;
#pragma unroll
    for (int kk = 0; kk < 4; ++kk) {
        const float4 a0 = ld4(arow + kk * 32);
        const float4 a1 = ld4(arow + kk * 32 + 4);
        const float av[8] = { a0.x, a0.y, a0.z, a0.w, a1.x, a1.y, a1.z, a1.w };
        bf16x8 Ah, Al;
#pragma unroll
        for (int j = 0; j < 8; ++j) {
            const short h = f2bf(av[j]);
            Ah[j] = h;
            Al[j] = f2bf(av[j] - bf2f(h));
        }
#pragma unroll
        for (int b = 0; b < 8; ++b) {
            const bf16x8 Bh = *reinterpret_cast<const bf16x8*>(&sBh[((kk * 8 + b) * 64 + lane) * 8]);
            const bf16x8 Bl = *reinterpret_cast<const bf16x8*>(&sBl[((kk * 8 + b) * 64 + lane) * 8]);
            C[b] = __builtin_amdgcn_mfma_f32_16x16x32_bf16(Ah, Bh, C[b], 0, 0, 0);
            C[b] = __builtin_amdgcn_mfma_f32_16x16x32_bf16(Al, Bh, C[b], 0, 0, 0);
            C[b] = __builtin_amdgcn_mfma_f32_16x16x32_bf16(Ah, Bl, C[b], 0, 0, 0);
        }
    }

    float s[4] = { 0.f, 0.f, 0.f, 0.f };
#pragma unroll
    for (int r = 0; r < 4; ++r) {
        float* orow = outp + (size_t)(m0 + (grp << 2) + r) * DD + ncol;
#pragma unroll
        for (int b = 0; b < 8; ++b) {
            const float a = C[b][r] + im[r] * wgi[b];
            const float g = 1.0f / (1.0f + expf(-a));
            const float o = fmaf(g, cvD[b][r] - xvD[b][r], xvD[b][r]);
            orow[b * 16] = o;
            s[r] += o * wp8[b];
        }
    }
#pragma unroll
    for (int off = 1; off < 16; off <<= 1) {
        s[0] += __shfl_xor(s[0], off, 64);
        s[1] += __shfl_xor(s[1], off, 64);
        s[2] += __shfl_xor(s[2], off, 64);
        s[3] += __shfl_xor(s[3], off, 64);
    }
    if (ncol < 4) {
        const float v = (ncol == 0) ? s[0] : (ncol == 1) ? s[1] : (ncol == 2) ? s[2] : s[3];
        prop[m0 + (grp << 2) + ncol] = v + bps;
    }
}

extern "C" void kernel_launch(void* const* d_in, const int* in_sizes, int n_in,
                              void* d_out, int out_size, void* d_ws, size_t ws_size,
                              hipStream_t stream) {
    const float* x   = (const float*)d_in[0];
    const int*   ei  = (const int*)d_in[1];
    const float* ea  = (const float*)d_in[2];
    const float* imp = (const float*)d_in[3];
    const float* We  = (const float*)d_in[4];
    const float* be  = (const float*)d_in[5];
    const float* Wc  = (const float*)d_in[6];
    const float* bc  = (const float*)d_in[7];
    const float* Wg  = (const float*)d_in[8];
    const float* bg  = (const float*)d_in[9];
    const float* Wp  = (const float*)d_in[10];
    const float* bp  = (const float*)d_in[11];

    float* out  = (float*)d_out;                 // [NN, DD]; doubles as agg
    float* prop = out + (size_t)NN * DD;         // [NN]
    float* agg  = out;                           // aliased (see k_conv note)

    // ws layout (~10.6 MB)
    int*  counts = (int*)d_ws;                              // NN
    int*  cursor = (int*)((char*)d_ws + 204800);            // NN
    int*  bsum   = (int*)((char*)d_ws + 409600);            // NB
    int*  bexcl  = (int*)((char*)d_ws + 413696);            // NB
    int2* sdat   = (int2*)((char*)d_ws + 1048576);          // NE int2
    int*  edst   = (int*)((char*)d_ws + 7448576);           // NE int

    hipMemsetAsync(counts, 0, NN * sizeof(int), stream);
    hipMemsetAsync(agg, 0, (size_t)NN * DD * sizeof(float), stream);
    hipLaunchKernelGGL(k_hist,    dim3(2048), dim3(256), 0, stream, ei, counts);
    hipLaunchKernelGGL(k_bsum,    dim3(NB),   dim3(256), 0, stream, counts, bsum);
    hipLaunchKernelGGL(k_scanb,   dim3(1),    dim3(256), 0, stream, bsum, bexcl);
    hipLaunchKernelGGL(k_rowptr,  dim3(NB),   dim3(256), 0, stream, counts, bexcl, cursor);
    hipLaunchKernelGGL(k_scatter, dim3(2048), dim3(256), 0, stream, ei, cursor, sdat, edst);
    hipLaunchKernelGGL(k_aggE,    dim3(2048), dim3(256), 0, stream,
                       x, ea, We, be, sdat, edst, agg);
    hipLaunchKernelGGL(k_conv,    dim3(782),  dim3(256), 0, stream, x, agg, Wc, bc, out);
    hipLaunchKernelGGL(k_gate,    dim3(782),  dim3(256), 0, stream,
                       x, out, imp, Wg, bg, Wp, bp, out, prop);
}

// Round 7
// 221.156 us; speedup vs baseline: 1.0690x; 1.0690x over previous
//
#include <hip/hip_runtime.h>

#define NN 50000
#define NE 800000
#define DD 128
#define ED 32
#define NB 196          // ceil(NN/256)
#define NC32 (NE / 32)  // 25000 exact

typedef short  bf16x8 __attribute__((ext_vector_type(8)));
typedef short  s16x8  __attribute__((ext_vector_type(8)));
typedef float  f32x4  __attribute__((ext_vector_type(4)));
typedef float  f32x16 __attribute__((ext_vector_type(16)));

__device__ __forceinline__ float4 ld4(const float* p) {
    return *reinterpret_cast<const float4*>(p);
}
__device__ __forceinline__ short f2bf(float f) {   // RTN-even f32 -> bf16 bits
    unsigned u = __float_as_uint(f);
    u += 0x7fffu + ((u >> 16) & 1u);
    return (short)(u >> 16);
}
__device__ __forceinline__ float bf2f(short h) {
    return __uint_as_float(((unsigned)(unsigned short)h) << 16);
}
__device__ __forceinline__ int sniff64(const int* ei) {
    // int64 indices < 2^32: every odd 32-bit word is zero.
    return ((ei[1] | ei[3] | ei[5] | ei[7]) == 0) ? 1 : 0;
}

// ============================================================ x -> bf16 table
__global__ __launch_bounds__(256)
void k_xcast(const float* __restrict__ x, unsigned short* __restrict__ xb) {
    const int t = blockIdx.x * 256 + threadIdx.x;     // 800000 threads exact
    const int base = t * 8;
    const float4 a = ld4(x + base), b = ld4(x + base + 4);
    s16x8 o;
    o[0] = f2bf(a.x); o[1] = f2bf(a.y); o[2] = f2bf(a.z); o[3] = f2bf(a.w);
    o[4] = f2bf(b.x); o[5] = f2bf(b.y); o[6] = f2bf(b.z); o[7] = f2bf(b.w);
    *reinterpret_cast<s16x8*>(xb + base) = o;
}

// ============================================================ CSR build
__global__ __launch_bounds__(256)
void k_hist(const int* __restrict__ ei, int* __restrict__ counts) {
    const int is64 = sniff64(ei);
    for (int e = blockIdx.x * blockDim.x + threadIdx.x; e < NE;
         e += gridDim.x * blockDim.x) {
        const int dst = ei[(long)(NE + e) << is64];
        atomicAdd(&counts[dst], 1);
    }
}

__global__ __launch_bounds__(256)
void k_bsum(const int* __restrict__ counts, int* __restrict__ bsum) {
    const int i = blockIdx.x * 256 + threadIdx.x;
    int c = (i < NN) ? counts[i] : 0;
#pragma unroll
    for (int off = 32; off; off >>= 1) c += __shfl_xor(c, off, 64);
    __shared__ int ws4[4];
    if ((threadIdx.x & 63) == 0) ws4[threadIdx.x >> 6] = c;
    __syncthreads();
    if (threadIdx.x == 0) bsum[blockIdx.x] = ws4[0] + ws4[1] + ws4[2] + ws4[3];
}

__global__ __launch_bounds__(256)
void k_scanb(const int* __restrict__ bsum, int* __restrict__ bexcl) {
    const int tid = threadIdx.x, lane = tid & 63, w = tid >> 6;
    const int v = (tid < NB) ? bsum[tid] : 0;
    int s = v;
#pragma unroll
    for (int off = 1; off < 64; off <<= 1) {
        const int t = __shfl_up(s, off, 64);
        if (lane >= off) s += t;
    }
    __shared__ int wsum[4], wexcl[4];
    if (lane == 63) wsum[w] = s;
    __syncthreads();
    if (tid == 0) {
        int r = 0;
#pragma unroll
        for (int k = 0; k < 4; ++k) { wexcl[k] = r; r += wsum[k]; }
    }
    __syncthreads();
    if (tid < NB) bexcl[tid] = wexcl[w] + s - v;
}

__global__ __launch_bounds__(256)
void k_rowptr(const int* __restrict__ counts, const int* __restrict__ bexcl,
              int* __restrict__ cursor) {
    const int tid = threadIdx.x, lane = tid & 63, w = tid >> 6;
    const int i = blockIdx.x * 256 + tid;
    const int c = (i < NN) ? counts[i] : 0;
    int s = c;
#pragma unroll
    for (int off = 1; off < 64; off <<= 1) {
        const int t = __shfl_up(s, off, 64);
        if (lane >= off) s += t;
    }
    __shared__ int wsum[4], wexcl[4];
    if (lane == 63) wsum[w] = s;
    __syncthreads();
    if (tid == 0) {
        int r = 0;
#pragma unroll
        for (int k = 0; k < 4; ++k) { wexcl[k] = r; r += wsum[k]; }
    }
    __syncthreads();
    if (i < NN) cursor[i] = bexcl[blockIdx.x] + wexcl[w] + s - c;
}

__global__ __launch_bounds__(256)
void k_scatter(const int* __restrict__ ei, int* __restrict__ cursor,
               int2* __restrict__ sdat, int* __restrict__ edst) {
    const int is64 = sniff64(ei);
    for (int e = blockIdx.x * blockDim.x + threadIdx.x; e < NE;
         e += gridDim.x * blockDim.x) {
        const int src = ei[(long)e << is64];
        const int dst = ei[(long)(NE + e) << is64];
        const int pos = atomicAdd(&cursor[dst], 1);
        sdat[pos] = make_int2(src, e);
        edst[pos] = dst;
    }
}

// ============================================================ aggregation
// One wave per 32-edge dst-sorted chunk (25000 waves). mfma 32x32x16_bf16:
// A = 32 ea rows (row=lane&31, k=(lane>>5)*8+i), B = We resident frags,
// C-init = bf16 x[src] gathers in D layout (col=lane&31 -> 64B full lines),
// 8 MFMAs (2 K-steps x 4 col-blocks). Epilogue relu(C+be), ballot-segmented
// reduce over equal-dst runs, 2 atomic instrs per segment (128 dims).
__global__ __launch_bounds__(256, 4)
void k_aggE(const unsigned short* __restrict__ xb, const float* __restrict__ ea,
            const float* __restrict__ We, const float* __restrict__ be,
            const int2* __restrict__ sdat, const int* __restrict__ edst,
            float* __restrict__ agg)
{
    const int lane = threadIdx.x & 63;
    const int col  = lane & 31;
    const int h    = lane >> 5;
    const int wid  = (blockIdx.x << 2) | (threadIdx.x >> 6);
    if (wid >= NC32) return;

    // B fragments: Bf[bb][s][i] = We[s*16 + h*8 + i][bb*32 + col]
    bf16x8 Bf[4][2];
    float  beb[4];
#pragma unroll
    for (int bb = 0; bb < 4; ++bb) {
#pragma unroll
        for (int s = 0; s < 2; ++s)
#pragma unroll
            for (int i = 0; i < 8; ++i)
                Bf[bb][s][i] = f2bf(We[(s * 16 + h * 8 + i) * DD + bb * 32 + col]);
        beb[bb] = be[bb * 32 + col];
    }

    const int2 dv   = sdat[wid * 32 + col];
    const int  dstv = edst[wid * 32 + col];

    // x-gather element offsets for this lane's 16 C rows (edges E(reg)=base+4h)
    unsigned off[16];
#pragma unroll
    for (int reg = 0; reg < 16; ++reg) {
        const int E = (reg & 3) + 8 * (reg >> 2) + 4 * h;
        const int src = __shfl(dv.x, E, 64);
        off[reg] = (unsigned)src * DD + col;
    }

    // C-init: C[bb][reg] = x[src_E][bb*32+col]  (bf16 -> f32, exact)
    f32x16 C[4];
#pragma unroll
    for (int bb = 0; bb < 4; ++bb)
#pragma unroll
        for (int reg = 0; reg < 16; ++reg)
            C[bb][reg] = __uint_as_float((unsigned)xb[off[reg] + bb * 32] << 16);

    // A fragments: ea row dv.y, step s covers k = s*16 + h*8 + i
    const float* ear = ea + (size_t)dv.y * ED + h * 8;
    const float4 a00 = ld4(ear),      a01 = ld4(ear + 4);
    const float4 a10 = ld4(ear + 16), a11 = ld4(ear + 20);
    bf16x8 Af0, Af1;
    Af0[0] = f2bf(a00.x); Af0[1] = f2bf(a00.y); Af0[2] = f2bf(a00.z); Af0[3] = f2bf(a00.w);
    Af0[4] = f2bf(a01.x); Af0[5] = f2bf(a01.y); Af0[6] = f2bf(a01.z); Af0[7] = f2bf(a01.w);
    Af1[0] = f2bf(a10.x); Af1[1] = f2bf(a10.y); Af1[2] = f2bf(a10.z); Af1[3] = f2bf(a10.w);
    Af1[4] = f2bf(a11.x); Af1[5] = f2bf(a11.y); Af1[6] = f2bf(a11.z); Af1[7] = f2bf(a11.w);

#pragma unroll
    for (int bb = 0; bb < 4; ++bb) {
        C[bb] = __builtin_amdgcn_mfma_f32_32x32x16_bf16(Af0, Bf[bb][0], C[bb], 0, 0, 0);
        C[bb] = __builtin_amdgcn_mfma_f32_32x32x16_bf16(Af1, Bf[bb][1], C[bb], 0, 0, 0);
    }

    // relu(+be)
#pragma unroll
    for (int bb = 0; bb < 4; ++bb)
#pragma unroll
        for (int reg = 0; reg < 16; ++reg)
            C[bb][reg] = fmaxf(C[bb][reg] + beb[bb], 0.0f);

    // segment boundaries over the 32 dst-sorted edges
    const int  prv  = __shfl(dstv, (col == 0) ? 0 : col - 1, 64);
    const bool flag = (lane < 32) && ((col == 0) || (dstv != prv));
    unsigned rem = (unsigned)(__ballot(flag) & 0xFFFFFFFFull);

    while (rem) {
        const int ms = __ffs((int)rem) - 1;
        rem &= rem - 1;
        const int hi = rem ? (__ffs((int)rem) - 1) : 32;
        const int d  = __shfl(dstv, ms, 64);

        float v0 = 0.f, v1 = 0.f, v2 = 0.f, v3 = 0.f;
#pragma unroll
        for (int reg = 0; reg < 16; ++reg) {
            const int E = (reg & 3) + 8 * (reg >> 2) + 4 * h;
            const float mk = (E >= ms && E < hi) ? 1.0f : 0.0f;
            v0 = fmaf(mk, C[0][reg], v0);
            v1 = fmaf(mk, C[1][reg], v1);
            v2 = fmaf(mk, C[2][reg], v2);
            v3 = fmaf(mk, C[3][reg], v3);
        }
        v0 += __shfl_xor(v0, 32, 64);
        v1 += __shfl_xor(v1, 32, 64);
        v2 += __shfl_xor(v2, 32, 64);
        v3 += __shfl_xor(v3, 32, 64);

        float* ar = agg + (size_t)d * DD + h * 64 + col;
        unsafeAtomicAdd(ar,      h ? v2 : v0);
        unsafeAtomicAdd(ar + 32, h ? v3 : v1);
    }
}

// ============================================================ conv (MFMA)
// conv = (x + agg) @ Wc + bc via split-bf16 (hi+lo, 3 MFMAs). agg aliases
// the conv output buffer (d_out): each block reads only its own 16 rows
// of agg/x before writing conv over them -> in-place safe.
__global__ __launch_bounds__(256)
void k_conv(const float* __restrict__ x, const float* agg,
            const float* __restrict__ Wc, const float* __restrict__ bc,
            float* conv)
{
    __shared__ short sBh[2048 * 8];
    __shared__ short sBl[2048 * 8];
    for (int idx = threadIdx.x; idx < 2048; idx += 256) {
        const int kk = idx >> 9;
        const int b  = (idx >> 6) & 7;
        const int l  = idx & 63;
        const int row0 = kk * 32 + ((l >> 4) << 3);
        const int col  = b * 16 + (l & 15);
        bf16x8 h8, l8;
#pragma unroll
        for (int j = 0; j < 8; ++j) {
            const float v = Wc[(row0 + j) * DD + col];
            const short h = f2bf(v);
            h8[j] = h;
            l8[j] = f2bf(v - bf2f(h));
        }
        *reinterpret_cast<bf16x8*>(&sBh[idx * 8]) = h8;
        *reinterpret_cast<bf16x8*>(&sBl[idx * 8]) = l8;
    }
    __syncthreads();

    const int lane = threadIdx.x & 63;
    const int ncol = lane & 15;
    const int krow = (lane >> 4) << 3;
    const int grp  = lane >> 4;
    const int wid  = (blockIdx.x << 2) | (threadIdx.x >> 6);
    if (wid >= NN / 16) return;

    float bcb[8];
#pragma unroll
    for (int b = 0; b < 8; ++b) bcb[b] = bc[b * 16 + ncol];

    const int m0 = wid * 16;
    const float* xrow = x   + (size_t)(m0 + ncol) * DD + krow;
    const float* grow = agg + (size_t)(m0 + ncol) * DD + krow;

    f32x4 C[8];
#pragma unroll
    for (int b = 0; b < 8; ++b) {
        f32x4 c = { bcb[b], bcb[b], bcb[b], bcb[b] };
        C[b] = c;
    }

#pragma unroll
    for (int kk = 0; kk < 4; ++kk) {
        const float4 x0 = ld4(xrow + kk * 32), x1 = ld4(xrow + kk * 32 + 4);
        const float4 g0 = ld4(grow + kk * 32), g1 = ld4(grow + kk * 32 + 4);
        const float av[8] = { x0.x + g0.x, x0.y + g0.y, x0.z + g0.z, x0.w + g0.w,
                              x1.x + g1.x, x1.y + g1.y, x1.z + g1.z, x1.w + g1.w };
        bf16x8 Ah, Al;
#pragma unroll
        for (int j = 0; j < 8; ++j) {
            const short h = f2bf(av[j]);
            Ah[j] = h;
            Al[j] = f2bf(av[j] - bf2f(h));
        }
#pragma unroll
        for (int b = 0; b < 8; ++b) {
            const bf16x8 Bh = *reinterpret_cast<const bf16x8*>(&sBh[((kk * 8 + b) * 64 + lane) * 8]);
            const bf16x8 Bl = *reinterpret_cast<const bf16x8*>(&sBl[((kk * 8 + b) * 64 + lane) * 8]);
            C[b] = __builtin_amdgcn_mfma_f32_16x16x32_bf16(Ah, Bh, C[b], 0, 0, 0);
            C[b] = __builtin_amdgcn_mfma_f32_16x16x32_bf16(Al, Bh, C[b], 0, 0, 0);
            C[b] = __builtin_amdgcn_mfma_f32_16x16x32_bf16(Ah, Bl, C[b], 0, 0, 0);
        }
    }

#pragma unroll
    for (int r = 0; r < 4; ++r) {
        float* crow = conv + (size_t)(m0 + (grp << 2) + r) * DD + ncol;
#pragma unroll
        for (int b = 0; b < 8; ++b) crow[b * 16] = C[b][r];
    }
}

// ============================================================ gate (MFMA)
__global__ __launch_bounds__(256)
void k_gate(const float* __restrict__ x, const float* conv,
            const float* __restrict__ imp, const float* __restrict__ Wg,
            const float* __restrict__ bg, const float* __restrict__ Wp,
            const float* __restrict__ bp, float* outp, float* __restrict__ prop)
{
    __shared__ short sBh[2048 * 8];
    __shared__ short sBl[2048 * 8];
    for (int idx = threadIdx.x; idx < 2048; idx += 256) {
        const int kk = idx >> 9;
        const int b  = (idx >> 6) & 7;
        const int l  = idx & 63;
        const int row0 = kk * 32 + ((l >> 4) << 3);
        const int col  = b * 16 + (l & 15);
        bf16x8 h8, l8;
#pragma unroll
        for (int j = 0; j < 8; ++j) {
            const float v = Wg[(row0 + j) * DD + col];
            const short h = f2bf(v);
            h8[j] = h;
            l8[j] = f2bf(v - bf2f(h));
        }
        *reinterpret_cast<bf16x8*>(&sBh[idx * 8]) = h8;
        *reinterpret_cast<bf16x8*>(&sBl[idx * 8]) = l8;
    }
    __syncthreads();

    const int lane = threadIdx.x & 63;
    const int ncol = lane & 15;
    const int krow = (lane >> 4) << 3;
    const int grp  = lane >> 4;
    const int wid  = (blockIdx.x << 2) | (threadIdx.x >> 6);
    if (wid >= NN / 16) return;

    float bgb[8], wgi[8], wp8[8];
#pragma unroll
    for (int b = 0; b < 8; ++b) {
        bgb[b] = bg[b * 16 + ncol];
        wgi[b] = Wg[DD * DD + b * 16 + ncol];   // importance row (row 128)
        wp8[b] = Wp[b * 16 + ncol];
    }
    const float bps = bp[0];

    const int m0 = wid * 16;

    float cvD[8][4], xvD[8][4], im[4];
#pragma unroll
    for (int r = 0; r < 4; ++r) {
        const int m = m0 + (grp << 2) + r;
        const float* cr = conv + (size_t)m * DD + ncol;
        const float* xr = x    + (size_t)m * DD + ncol;
        im[r] = imp[m];
#pragma unroll
        for (int b = 0; b < 8; ++b) { cvD[b][r] = cr[b * 16]; xvD[b][r] = xr[b * 16]; }
    }

    f32x4 C[8];
#pragma unroll
    for (int b = 0; b < 8; ++b) {
        f32x4 c = { bgb[b], bgb[b], bgb[b], bgb[b] };
        C[b] = c;
    }

    const float* arow = conv + (size_t)(m0 + ncol) * DD + krow;
#pragma unroll
    for (int kk = 0; kk < 4; ++kk) {
        const float4 a0 = ld4(arow + kk * 32);
        const float4 a1 = ld4(arow + kk * 32 + 4);
        const float av[8] = { a0.x, a0.y, a0.z, a0.w, a1.x, a1.y, a1.z, a1.w };
        bf16x8 Ah, Al;
#pragma unroll
        for (int j = 0; j < 8; ++j) {
            const short h = f2bf(av[j]);
            Ah[j] = h;
            Al[j] = f2bf(av[j] - bf2f(h));
        }
#pragma unroll
        for (int b = 0; b < 8; ++b) {
            const bf16x8 Bh = *reinterpret_cast<const bf16x8*>(&sBh[((kk * 8 + b) * 64 + lane) * 8]);
            const bf16x8 Bl = *reinterpret_cast<const bf16x8*>(&sBl[((kk * 8 + b) * 64 + lane) * 8]);
            C[b] = __builtin_amdgcn_mfma_f32_16x16x32_bf16(Ah, Bh, C[b], 0, 0, 0);
            C[b] = __builtin_amdgcn_mfma_f32_16x16x32_bf16(Al, Bh, C[b], 0, 0, 0);
            C[b] = __builtin_amdgcn_mfma_f32_16x16x32_bf16(Ah, Bl, C[b], 0, 0, 0);
        }
    }

    float s[4] = { 0.f, 0.f, 0.f, 0.f };
#pragma unroll
    for (int r = 0; r < 4; ++r) {
        float* orow = outp + (size_t)(m0 + (grp << 2) + r) * DD + ncol;
#pragma unroll
        for (int b = 0; b < 8; ++b) {
            const float a = C[b][r] + im[r] * wgi[b];
            const float g = 1.0f / (1.0f + expf(-a));
            const float o = fmaf(g, cvD[b][r] - xvD[b][r], xvD[b][r]);
            orow[b * 16] = o;
            s[r] += o * wp8[b];
        }
    }
#pragma unroll
    for (int off = 1; off < 16; off <<= 1) {
        s[0] += __shfl_xor(s[0], off, 64);
        s[1] += __shfl_xor(s[1], off, 64);
        s[2] += __shfl_xor(s[2], off, 64);
        s[3] += __shfl_xor(s[3], off, 64);
    }
    if (ncol < 4) {
        const float v = (ncol == 0) ? s[0] : (ncol == 1) ? s[1] : (ncol == 2) ? s[2] : s[3];
        prop[m0 + (grp << 2) + ncol] = v + bps;
    }
}

extern "C" void kernel_launch(void* const* d_in, const int* in_sizes, int n_in,
                              void* d_out, int out_size, void* d_ws, size_t ws_size,
                              hipStream_t stream) {
    const float* x   = (const float*)d_in[0];
    const int*   ei  = (const int*)d_in[1];
    const float* ea  = (const float*)d_in[2];
    const float* imp = (const float*)d_in[3];
    const float* We  = (const float*)d_in[4];
    const float* be  = (const float*)d_in[5];
    const float* Wc  = (const float*)d_in[6];
    const float* bc  = (const float*)d_in[7];
    const float* Wg  = (const float*)d_in[8];
    const float* bg  = (const float*)d_in[9];
    const float* Wp  = (const float*)d_in[10];
    const float* bp  = (const float*)d_in[11];

    float* out  = (float*)d_out;                 // [NN, DD]; doubles as agg
    float* prop = out + (size_t)NN * DD;         // [NN]
    float* agg  = out;                           // aliased (see k_conv note)

    // ws layout (~23.5 MB)
    int*            counts = (int*)d_ws;                          // NN
    int*            cursor = (int*)((char*)d_ws + 204800);        // NN
    int*            bsum   = (int*)((char*)d_ws + 409600);        // NB
    int*            bexcl  = (int*)((char*)d_ws + 413696);        // NB
    int2*           sdat   = (int2*)((char*)d_ws + 1048576);      // NE int2
    int*            edst   = (int*)((char*)d_ws + 7448576);       // NE int
    unsigned short* xb     = (unsigned short*)((char*)d_ws + 10649600); // NN*DD bf16

    hipMemsetAsync(counts, 0, NN * sizeof(int), stream);
    hipMemsetAsync(agg, 0, (size_t)NN * DD * sizeof(float), stream);
    hipLaunchKernelGGL(k_xcast,   dim3(3125), dim3(256), 0, stream, x, xb);
    hipLaunchKernelGGL(k_hist,    dim3(2048), dim3(256), 0, stream, ei, counts);
    hipLaunchKernelGGL(k_bsum,    dim3(NB),   dim3(256), 0, stream, counts, bsum);
    hipLaunchKernelGGL(k_scanb,   dim3(1),    dim3(256), 0, stream, bsum, bexcl);
    hipLaunchKernelGGL(k_rowptr,  dim3(NB),   dim3(256), 0, stream, counts, bexcl, cursor);
    hipLaunchKernelGGL(k_scatter, dim3(2048), dim3(256), 0, stream, ei, cursor, sdat, edst);
    hipLaunchKernelGGL(k_aggE,    dim3(6250), dim3(256), 0, stream,
                       xb, ea, We, be, sdat, edst, agg);
    hipLaunchKernelGGL(k_conv,    dim3(782),  dim3(256), 0, stream, x, agg, Wc, bc, out);
    hipLaunchKernelGGL(k_gate,    dim3(782),  dim3(256), 0, stream,
                       x, out, imp, Wg, bg, Wp, bp, out, prop);
}